// Round 10
// baseline (66.155 us; speedup 1.0000x reference)
//
#include <hip/hip_runtime.h>
#include <hip/hip_bf16.h>

#define DD 256
#define SS 4096

typedef __bf16 bf16x8 __attribute__((ext_vector_type(8)));
typedef float  f32x4  __attribute__((ext_vector_type(4)));

__device__ __forceinline__ float fast_tanh(float x) {
  float e = exp2f(x * 2.885390081777927f);   // exp(2x)
  return 1.0f - 2.0f / (e + 1.0f);
}

// DPP helpers: reduce across the 16-lane row (lg = lane&15) within each g-group
template<int CTRL>
__device__ __forceinline__ float dpp_mov(float v) {
  return __int_as_float(__builtin_amdgcn_update_dpp(0, __float_as_int(v), CTRL, 0xF, 0xF, true));
}
__device__ __forceinline__ float row16_sum(float v) {
  v += dpp_mov<0xB1>(v);   // quad_perm xor1
  v += dpp_mov<0x4E>(v);   // quad_perm xor2
  v += dpp_mov<0x124>(v);  // row_ror:4
  v += dpp_mov<0x128>(v);  // row_ror:8
  return v;
}
__device__ __forceinline__ float row16_max(float v) {
  v = fmaxf(v, dpp_mov<0xB1>(v));
  v = fmaxf(v, dpp_mov<0x4E>(v));
  v = fmaxf(v, dpp_mov<0x124>(v));
  v = fmaxf(v, dpp_mov<0x128>(v));
  return v;
}

// Prep: W [256,256] fp32 -> fragment-ordered bf16 WF (in d_ws).
// Chunk c = ((n0*8+ks)*64 + lane) holds 8 bf16: W[ks*32+(lane>>4)*8+i][n0*16+(lane&15)]
__global__ __launch_bounds__(256) void prep_kernel(
    const float* __restrict__ W, __bf16* __restrict__ WF)
{
  const int c = blockIdx.x * 256 + threadIdx.x;   // 8192 chunks
  const int lane_c = c & 63;
  const int ks  = (c >> 6) & 7;
  const int n0  = c >> 9;
  const int col = n0 * 16 + (lane_c & 15);
  const int k0  = ks * 32 + (lane_c >> 4) * 8;
  const float* wp = W + k0 * DD + col;
  bf16x8 fr;
  #pragma unroll
  for (int i = 0; i < 8; ++i) fr[i] = (__bf16)wp[i * DD];
  *reinterpret_cast<bf16x8*>(WF + (size_t)c * 8) = fr;
}

#define PACK(dst, f0, f1) { \
  bf16x8 _fr; \
  _fr[0] = (__bf16)(f0).x; _fr[1] = (__bf16)(f0).y; \
  _fr[2] = (__bf16)(f0).z; _fr[3] = (__bf16)(f0).w; \
  _fr[4] = (__bf16)(f1).x; _fr[5] = (__bf16)(f1).y; \
  _fr[6] = (__bf16)(f1).z; _fr[7] = (__bf16)(f1).w; \
  (dst) = _fr; }

// One 16x16 output tile: 8 ds_read_b128 B-frags + 8 MFMA + tanh*V epilogue
#define TILE(aX, spX, n0q) { \
  const __bf16* _bp = WtF + ((size_t)((n0q) * 8 * 64 + lane)) * 8; \
  bf16x8 _bfr[8]; \
  _Pragma("unroll") \
  for (int _ks = 0; _ks < 8; ++_ks) \
    _bfr[_ks] = *reinterpret_cast<const bf16x8*>(_bp + (size_t)_ks * 512); \
  f32x4 _acc = {0.f, 0.f, 0.f, 0.f}; \
  _Pragma("unroll") \
  for (int _ks = 0; _ks < 8; ++_ks) \
    _acc = __builtin_amdgcn_mfma_f32_16x16x32_bf16(aX[_ks], _bfr[_ks], _acc, 0, 0, 0); \
  const int _col = (n0q) * 16 + lg; \
  const float _vc = Vs[_col], _bc = Bs[_col]; \
  _Pragma("unroll") \
  for (int _r = 0; _r < 4; ++_r) \
    spX[_r] += fast_tanh(_acc[_r] + _bc) * _vc; }

// Phase-3 (per 16-row chunk, online): logit reduce -> per-row l0 -> chunk max
// -> rescale running (M,S,Pacc) and accumulate this chunk's contribution.
#define PHASE3(aX, spX) { \
  _Pragma("unroll") \
  for (int _r = 0; _r < 4; ++_r) spX[_r] = row16_sum(spX[_r]); \
  const int _src = ((lg >> 2) << 4) | lg; \
  float _l0 = 0.f; \
  _Pragma("unroll") \
  for (int _r = 0; _r < 4; ++_r) { \
    float _v0 = __shfl(spX[_r], _src, 64); \
    if ((lg & 3) == _r) _l0 = _v0; \
  } \
  const float _mc = row16_max(_l0); \
  const float _Mn = fmaxf(Mrun, _mc); \
  const float _f  = __expf(Mrun - _Mn); \
  Mrun = _Mn; \
  const float _w0 = __expf(_l0 - _Mn); \
  Srun = Srun * _f + row16_sum(_w0); \
  _Pragma("unroll") \
  for (int _ks = 0; _ks < 8; ++_ks) { \
    float _p8[8]; \
    _Pragma("unroll") \
    for (int _i = 0; _i < 8; ++_i) _p8[_i] = _w0 * (float)aX[_ks][_i]; \
    _Pragma("unroll") \
    for (int _i = 0; _i < 8; ++_i) _p8[_i] = row16_sum(_p8[_i]); \
    if (lg < 2) { \
      float4 _nv = (lg == 0) ? make_float4(_p8[0], _p8[1], _p8[2], _p8[3]) \
                             : make_float4(_p8[4], _p8[5], _p8[6], _p8[7]); \
      float4* _pp = reinterpret_cast<float4*>(&Pacc[wave][_ks * 32 + g * 8 + lg * 4]); \
      float4 _ov = *_pp; \
      _ov.x = _f * _ov.x + _nv.x; _ov.y = _f * _ov.y + _nv.y; \
      _ov.z = _f * _ov.z + _nv.z; _ov.w = _f * _ov.w + _nv.w; \
      *_pp = _ov; \
    } \
  } }

// Fused: 256 blocks x 1024 thr (16 waves/CU, 1 block/CU). Wave owns 32 rows
// as TWO 16-row chunks with online softmax. Chunk-0 loads primed at entry
// (overlap W staging); chunk-1 loads issued in two pinned halves under
// chunk-0's tile pass (sched_barrier(0) prevents the scheduler sinking them).
__global__ __launch_bounds__(1024, 1) __attribute__((amdgpu_waves_per_eu(4)))
void fused_kernel(
    const float* __restrict__ X, const __bf16* __restrict__ WF,
    const float* __restrict__ bias, const float* __restrict__ V,
    float* __restrict__ Pout, float* __restrict__ Mout, float* __restrict__ Sout)
{
  __shared__ __bf16 WtF[8192 * 8];    // 128 KB, fragment-ordered
  __shared__ float  Pacc[16][DD];     // 16 KB, per-wave running partial
  __shared__ float  Vs[DD];
  __shared__ float  Bs[DD];
  __shared__ float  wred[16];
  __shared__ float  sred[16];

  const int t = threadIdx.x;
  const int wave = t >> 6, lane = t & 63;
  const int g  = lane >> 4;    // k-group 0..3 (DPP row)
  const int lg = lane & 15;    // sub-lane 0..15 (= row within chunk)
  const size_t rowBase = (size_t)blockIdx.x * 512 + (size_t)wave * 32;

  // ---- Prime chunk-0 X loads FIRST (HBM busy from t=0) ----
  float4 raw[16];
  const float* xr0 = X + (rowBase + lg) * DD;
  #pragma unroll
  for (int ks = 0; ks < 8; ++ks) {
    const float4* p = reinterpret_cast<const float4*>(xr0 + ks * 32 + g * 8);
    raw[2 * ks]     = p[0];
    raw[2 * ks + 1] = p[1];
  }
  __builtin_amdgcn_sched_barrier(0);   // pin: loads must issue before staging

  // ---- Stage W -> LDS (coalesced), V/bias, zero Pacc ----
  {
    const uint4* src = reinterpret_cast<const uint4*>(WF);
    uint4* dst = reinterpret_cast<uint4*>(WtF);
    #pragma unroll
    for (int i = 0; i < 8; ++i) dst[t + i * 1024] = src[t + i * 1024];
  }
  if (t < DD) { Vs[t] = V[t]; Bs[t] = bias[t]; }
  {
    float* pz = &Pacc[0][0];
    #pragma unroll
    for (int i = 0; i < 4; ++i) pz[t + i * 1024] = 0.f;
  }
  __syncthreads();

  float Mrun = -1e30f, Srun = 0.f;

  // ---- Chunk 0: convert, then prefetch chunk-1 under the tile pass ----
  bf16x8 a[8];
  #pragma unroll
  for (int ks = 0; ks < 8; ++ks) PACK(a[ks], raw[2 * ks], raw[2 * ks + 1]);

  const float* xr1 = X + (rowBase + 16 + lg) * DD;
  #pragma unroll
  for (int ks = 0; ks < 4; ++ks) {     // chunk-1 first half in flight
    const float4* p = reinterpret_cast<const float4*>(xr1 + ks * 32 + g * 8);
    raw[2 * ks]     = p[0];
    raw[2 * ks + 1] = p[1];
  }
  __builtin_amdgcn_sched_barrier(0);

  float sp[4] = {0.f, 0.f, 0.f, 0.f};
  #pragma unroll 1
  for (int n0 = 0; n0 < 8; ++n0) TILE(a, sp, n0);

  #pragma unroll
  for (int ks = 4; ks < 8; ++ks) {     // chunk-1 second half in flight
    const float4* p = reinterpret_cast<const float4*>(xr1 + ks * 32 + g * 8);
    raw[2 * ks]     = p[0];
    raw[2 * ks + 1] = p[1];
  }
  __builtin_amdgcn_sched_barrier(0);

  #pragma unroll 1
  for (int n0 = 8; n0 < 16; ++n0) TILE(a, sp, n0);

  PHASE3(a, sp);

  // ---- Chunk 1 ----
  #pragma unroll
  for (int ks = 0; ks < 8; ++ks) PACK(a[ks], raw[2 * ks], raw[2 * ks + 1]);

  float sq[4] = {0.f, 0.f, 0.f, 0.f};
  #pragma unroll 1
  for (int n0 = 0; n0 < 16; ++n0) TILE(a, sq, n0);

  PHASE3(a, sq);

  if (lane == 0) { wred[wave] = Mrun; sred[wave] = Srun; }
  __syncthreads();

  // ---- Phase 4: cross-wave combine (per-wave M rescale) ----
  float MB = -1e30f;
  #pragma unroll
  for (int w = 0; w < 16; ++w) MB = fmaxf(MB, wred[w]);
  if (t < DD) {
    float s = 0.f;
    #pragma unroll
    for (int w = 0; w < 16; ++w) s += __expf(wred[w] - MB) * Pacc[w][t];
    Pout[(size_t)blockIdx.x * DD + t] = s;
  }
  if (t == 0) {
    float ss = 0.f;
    #pragma unroll
    for (int w = 0; w < 16; ++w) ss += __expf(wred[w] - MB) * sred[w];
    Sout[blockIdx.x] = ss;
    Mout[blockIdx.x] = MB;
  }
}

// Combine: per batch, merge the 8 block partials with max-rescale.
__global__ __launch_bounds__(256) void combine_kernel(
    const float* __restrict__ P, const float* __restrict__ Mb,
    const float* __restrict__ Sb, float* __restrict__ ctx)
{
  const int b = blockIdx.x, t = threadIdx.x;
  float Mg = -1e30f;
  #pragma unroll
  for (int k = 0; k < 8; ++k) Mg = fmaxf(Mg, Mb[b * 8 + k]);
  float denom = 0.f, acc = 0.f;
  #pragma unroll
  for (int k = 0; k < 8; ++k) {
    const float f = __expf(Mb[b * 8 + k] - Mg);
    denom += f * Sb[b * 8 + k];
    acc   += f * P[(size_t)(b * 8 + k) * DD + t];
  }
  ctx[b * DD + t] = acc / denom;
}

extern "C" void kernel_launch(void* const* d_in, const int* in_sizes, int n_in,
                              void* d_out, int out_size, void* d_ws, size_t ws_size,
                              hipStream_t stream) {
  const float* X    = (const float*)d_in[0];  // [32,4096,256] fp32
  const float* W    = (const float*)d_in[1];  // [256,256]
  const float* bias = (const float*)d_in[2];  // [256]
  const float* V    = (const float*)d_in[3];  // [256,1]
  float* ctx = (float*)d_out;                 // [32,256]

  __bf16* WF = (__bf16*)d_ws;                       // 128 KB, fragment-ordered
  float* P = (float*)((char*)d_ws + 128 * 1024);    // [256,256] = 256 KB
  float* M = P + 256 * DD;                          // [256]
  float* S = M + 256;                               // [256]

  prep_kernel<<<32, 256, 0, stream>>>(W, WF);
  fused_kernel<<<256, 1024, 0, stream>>>(X, WF, bias, V, P, M, S);
  combine_kernel<<<32, 256, 0, stream>>>(P, M, S, ctx);
}